// Round 3
// baseline (252.730 us; speedup 1.0000x reference)
//
#include <hip/hip_runtime.h>
#include <hip/hip_bf16.h>
#include <stdint.h>

// Problem constants (from reference)
#define N_NODES 50000
#define N_EDGES 800000
#define N_ENTS  200000
#define N_RELS  500
#define DIM     128

#define DEGS 32   // deg counter stride (ints): 1 counter per 128B L2 line.
#define CAP  64   // slots per node. deg ~ Poisson(16); P(any node > 64) ~ 1e-20.

// invalid-edge record: points at zeroed dummy rows (afull row 50000, rel row 500)
#define ZERO_REC ((int)(50000u | (500u << 16)))

using f32x4  = __attribute__((ext_vector_type(4))) float;
using f32x2  = __attribute__((ext_vector_type(2))) float;
using bf16x8 = __attribute__((ext_vector_type(8))) short;  // 8 bf16 = 4 VGPRs

static __device__ __forceinline__ ushort f_to_bf16(float f) {
    __hip_bfloat16 h = __float2bfloat16(f);
    return *reinterpret_cast<ushort*>(&h);
}
static __device__ __forceinline__ uint pack2(float a, float b) {
    return (uint)f_to_bf16(a) | ((uint)f_to_bf16(b) << 16);
}
static __device__ __forceinline__ float blo(uint u) { return __uint_as_float(u << 16); }
// packed unpack: uint holding 2 bf16 -> f32x2 {lo, hi}; downstream adds become
// v_pk_add_f32 (2 cols/instr): 6 VALU per uint vs 8 scalar (r7).
static __device__ __forceinline__ f32x2 up2(uint u) {
    return f32x2{__uint_as_float(u << 16), __uint_as_float(u & 0xffff0000u)};
}

// ---------------------------------------------------------------------------
// K_EDGE: RANK+SLOT pass, 1 edge/thread (r6 lesson: max TLP — 4 edges/thread
// at 1/4 threads exposed the atomic->dependent-store latency chain, +27us).
// r7: split into its own dispatch so rocprof times it separately from the
// gather pass (k_front at 58us defied all first-principles models; need to
// know which pass owns it).
__global__ __launch_bounds__(256) void k_edge(
        const int* __restrict__ dst, const int* __restrict__ src,
        const int* __restrict__ etype,
        int* __restrict__ deg, uint* __restrict__ srcpk) {
    int e = blockIdx.x * 256 + threadIdx.x;
    if (e < N_EDGES) {
        int dn = dst[e];
        uint rec = (uint)src[e] | ((uint)etype[e] << 16);
        int r = atomicAdd(&deg[dn * DEGS], 1);
        if (r < CAP) srcpk[dn * CAP + r] = rec;
    }
}

// ---------------------------------------------------------------------------
// K_REST: the non-atomic front work:
//   blk [0,3125):    gather h = bf16(prev[node_id]) into h-half of afull rows
//                    afull row layout: [ apre (128) | h (128) ] bf16, stride 256
//   blk [3125,3379): weight-prep: B^T bf16 (WfT) + rel bf16
//   blk 3379:        zero the dummy rows (afull row 50000, rel_bf row 500)
__global__ __launch_bounds__(256) void k_rest(
        const float* __restrict__ prev, const int* __restrict__ node_id,
        ushort* __restrict__ afull,
        const float* __restrict__ rel, ushort* __restrict__ rel_bf,
        const float* __restrict__ Wn, const float* __restrict__ Wl,
        ushort* __restrict__ WfT) {
    int blk = blockIdx.x;
    if (blk < 3125) {
        int i = blk * 256 + threadIdx.x;            // 800,000 = N_NODES*16 exactly
        int row = i >> 4, c = (i & 15) * 8;
        int nid = node_id[row];
        const float* p = prev + (size_t)nid * DIM + c;
        float4 v0 = *(const float4*)p;
        float4 v1 = *(const float4*)(p + 4);
        uint4 w;
        w.x = pack2(v0.x, v0.y);
        w.y = pack2(v0.z, v0.w);
        w.z = pack2(v1.x, v1.y);
        w.w = pack2(v1.z, v1.w);
        *(uint4*)(afull + (size_t)row * 256 + 128 + c) = w;
    } else if (blk < 3379) {
        int i = (blk - 3125) * 256 + threadIdx.x;
        if (i < 128 * 256) {            // WfT[n][k] = k<128 ? Wn[k][n] : Wl[k-128][n]
            int n = i >> 8, k = i & 255;
            float v = (k < 128) ? Wn[k * 128 + n] : Wl[(k - 128) * 128 + n];
            WfT[i] = f_to_bf16(v);
        } else {
            int j = i - 128 * 256;      // rel fp32 -> bf16, 2 elems/thread
            if (j < N_RELS * 64) {
                float2 v = *(const float2*)(rel + j * 2);
                *(uint*)(rel_bf + j * 2) = pack2(v.x, v.y);
            }
        }
    } else {
        int t = threadIdx.x;            // zero dummy rows (ws is 0xAA-poisoned)
        if (t < 128)       ((uint*)(afull + (size_t)50000 * 256))[t] = 0u;
        else if (t < 192)  ((uint*)(rel_bf + 500 * 128))[t - 128]    = 0u;
    }
}

// ---------------------------------------------------------------------------
// K_AGG: per-node aggregation, 1 wave per node.
// apre[n] = bf16( (1/deg) * sum_{slots of n} (h[src_e] + rel[etype_e]) )
// Lane-group scheme: group g (lanes 16g..16g+15) covers an edge's FULL
// 256B h-row / rel-row with one dwordx4 per lane. Invalid slots point at
// zeroed dummy rows (no cndmask in the hot loop; dummies are L1-hot).
// 16 edges/iter main loop (8 dwordx4 in flight); r7: f32x2 packed accum
// (v_pk_add_f32, -25% VALU) + 4-edge-granular tail (avg dummy gathers per
// node drop ~8 -> ~2).
__global__ __launch_bounds__(256) void k_agg(ushort* __restrict__ afull,
                                             const ushort* __restrict__ rel_bf,
                                             const uint* __restrict__ srcpk,
                                             const int* __restrict__ deg) {
    int wave = threadIdx.x >> 6, lane = threadIdx.x & 63;
    int n = blockIdx.x * 4 + wave;
    if (n >= N_NODES) return;
    int d = deg[n * DEGS];
    int cnt = min(d, CAP);
    int g = lane >> 4, q = lane & 15;           // group, quarter-position
    const ushort* hb = afull + 128 + q * 8;     // + srow*256
    const ushort* rb = rel_bf + q * 8;          // + t*128
    f32x2 ac0 = {0.f, 0.f}, ac1 = {0.f, 0.f}, ac2 = {0.f, 0.f}, ac3 = {0.f, 0.f};

#define ACCP(hv, rv)                        \
    ac0 += up2(hv.x) + up2(rv.x);           \
    ac1 += up2(hv.y) + up2(rv.y);           \
    ac2 += up2(hv.z) + up2(rv.z);           \
    ac3 += up2(hv.w) + up2(rv.w);

    int rec = (lane < cnt) ? (int)srcpk[n * CAP + lane] : ZERO_REC;
    int j = 0;
    for (; j + 16 <= cnt; j += 16) {            // 16 edges per iter (4 per group)
        uint e0 = (uint)__shfl(rec, j + g);
        uint e1 = (uint)__shfl(rec, j + 4 + g);
        uint e2 = (uint)__shfl(rec, j + 8 + g);
        uint e3 = (uint)__shfl(rec, j + 12 + g);
        uint4 h0 = *(const uint4*)(hb + (size_t)(e0 & 0xffffu) * 256);
        uint4 r0 = *(const uint4*)(rb + (e0 >> 16) * 128);
        uint4 h1 = *(const uint4*)(hb + (size_t)(e1 & 0xffffu) * 256);
        uint4 r1 = *(const uint4*)(rb + (e1 >> 16) * 128);
        uint4 h2 = *(const uint4*)(hb + (size_t)(e2 & 0xffffu) * 256);
        uint4 r2 = *(const uint4*)(rb + (e2 >> 16) * 128);
        uint4 h3 = *(const uint4*)(hb + (size_t)(e3 & 0xffffu) * 256);
        uint4 r3 = *(const uint4*)(rb + (e3 >> 16) * 128);
        ACCP(h0, r0);
        ACCP(h1, r1);
        ACCP(h2, r2);
        ACCP(h3, r3);
    }
    for (int s = j; s < cnt; s += 4) {          // tail: 4 edges per sub-step
        uint e = (uint)__shfl(rec, s + g);      // s+g <= 63 always (s stepped
        uint4 h = *(const uint4*)(hb + (size_t)(e & 0xffffu) * 256);   // by 4 from
        uint4 r = *(const uint4*)(rb + (e >> 16) * 128);               // 16-mult j)
        ACCP(h, r);
    }
#undef ACCP

    // cross-group reduction: groups 0..3 hold partial sums of the same columns
    float acc[8] = {ac0.x, ac0.y, ac1.x, ac1.y, ac2.x, ac2.y, ac3.x, ac3.y};
#pragma unroll
    for (int i = 0; i < 8; i++) {
        acc[i] += __shfl_xor(acc[i], 16);
        acc[i] += __shfl_xor(acc[i], 32);
    }
    float norm = (d > 0) ? 1.0f / (float)d : 0.0f;
    if (g == 0) {                                // 16 lanes store the full row
        uint4 w;
        w.x = pack2(acc[0] * norm, acc[1] * norm);
        w.y = pack2(acc[2] * norm, acc[3] * norm);
        w.z = pack2(acc[4] * norm, acc[5] * norm);
        w.w = pack2(acc[6] * norm, acc[7] * norm);
        *(uint4*)(afull + (size_t)n * 256 + q * 8) = w;
    }
}

// ---------------------------------------------------------------------------
// K_MM: fused GEMM  out = relu( [apre|h] @ [Wn;Wl] ),  M=50000, N=128, K=256
// mfma_f32_16x16x32_bf16; each wave: 2 row-tiles x 8 col-tiles. fp32 output.
// Absorbs k_fixup: epilogue checks deg per row; deg==0 rows (expected ~0 of
// 50000) take a slow VALU path out = relu(h @ We).
// LDSK=264 B-reads verified conflict-free: each 8-lane b128 phase group
// (fixed quad, consecutive m) covers 8 distinct 4-bank windows.
#define LDSK 264   // padded k-stride (elems)
__global__ __launch_bounds__(256) void k_mm(const ushort* __restrict__ afull,
                                            const ushort* __restrict__ WfT,
                                            const int* __restrict__ deg,
                                            const float* __restrict__ We,
                                            float* __restrict__ out) {
    __shared__ ushort wl[128 * LDSK];   // 67,584 B
    for (int idx = threadIdx.x; idx < 128 * 32; idx += 256) {
        int n = idx >> 5, p = idx & 31;
        uint4 v = *(const uint4*)(WfT + n * 256 + p * 8);
        *(uint4*)(&wl[n * LDSK + p * 8]) = v;
    }
    __syncthreads();

    int wave = threadIdx.x >> 6, lane = threadIdx.x & 63;
    int m = lane & 15, quad = lane >> 4;
    int rowBase = blockIdx.x * 128 + wave * 32;

    f32x4 acc[2][8];
#pragma unroll
    for (int rt = 0; rt < 2; rt++)
#pragma unroll
        for (int ct = 0; ct < 8; ct++) acc[rt][ct] = f32x4{0.f, 0.f, 0.f, 0.f};

    int r0 = rowBase + m;      if (r0 > N_NODES - 1) r0 = N_NODES - 1;  // clamp tail
    int r1 = rowBase + 16 + m; if (r1 > N_NODES - 1) r1 = N_NODES - 1;
    const ushort* pa0 = afull + (size_t)r0 * 256 + quad * 8;
    const ushort* pa1 = afull + (size_t)r1 * 256 + quad * 8;

#pragma unroll
    for (int ks = 0; ks < 8; ks++) {
        bf16x8 a0 = *(const bf16x8*)(pa0 + ks * 32);   // A[m][k]: k = quad*8+j
        bf16x8 a1 = *(const bf16x8*)(pa1 + ks * 32);
#pragma unroll
        for (int ct = 0; ct < 8; ct++) {
            bf16x8 b = *(const bf16x8*)(&wl[(ct * 16 + m) * LDSK + ks * 32 + quad * 8]);
            acc[0][ct] = __builtin_amdgcn_mfma_f32_16x16x32_bf16(a0, b, acc[0][ct], 0, 0, 0);
            acc[1][ct] = __builtin_amdgcn_mfma_f32_16x16x32_bf16(a1, b, acc[1][ct], 0, 0, 0);
        }
    }

    // epilogue: C/D layout col=lane&15, row=(lane>>4)*4+reg
#pragma unroll
    for (int rt = 0; rt < 2; rt++) {
        int rbase = rowBase + rt * 16 + quad * 4;
#pragma unroll
        for (int reg = 0; reg < 4; reg++) {
            int grow = rbase + reg;
            if (grow < N_NODES) {
                if (__builtin_expect(deg[grow * DEGS] == 0, 0)) {
                    // rare: no in-edges -> out = relu(h @ evolve_loop_weight).
                    // 16 lanes of this quad share the row; lane m covers cols m+16ct.
#pragma unroll 1
                    for (int ct = 0; ct < 8; ct++) {
                        int col = ct * 16 + m;
                        float a = 0.f;
#pragma unroll 1
                        for (int k = 0; k < 128; k++) {
                            float hv = blo((uint)afull[(size_t)grow * 256 + 128 + k]);
                            a += hv * We[k * 128 + col];
                        }
                        out[(size_t)grow * 128 + col] = a > 0.f ? a : 0.f;
                    }
                } else {
#pragma unroll
                    for (int ct = 0; ct < 8; ct++) {
                        float v = acc[rt][ct][reg];
                        out[(size_t)grow * 128 + ct * 16 + m] = v > 0.f ? v : 0.f;
                    }
                }
            }
        }
    }
}

// ---------------------------------------------------------------------------
extern "C" void kernel_launch(void* const* d_in, const int* in_sizes, int n_in,
                              void* d_out, int out_size, void* d_ws, size_t ws_size,
                              hipStream_t stream) {
    const float* prev  = (const float*)d_in[0];  // prev_ent_embs   [200000,128] f32
    const float* rel   = (const float*)d_in[1];  // rel_embs        [500,128]    f32
    const float* Wl    = (const float*)d_in[2];  // loop_weight     [128,128]    f32
    const float* We    = (const float*)d_in[3];  // evolve_loop_w   [128,128]    f32
    const float* Wn    = (const float*)d_in[4];  // weight_neighbor [128,128]    f32
    const int* node_id = (const int*)d_in[5];    // [50000]  int32
    const int* src     = (const int*)d_in[6];    // [800000] int32
    const int* dst     = (const int*)d_in[7];    // [800000] int32
    const int* etype   = (const int*)d_in[8];    // [800000] int32
    float* out = (float*)d_out;                  // [50000,128] f32

    // workspace layout (~45 MB; afull/rel_bf each carry a zeroed dummy row)
    char* ws = (char*)d_ws;
    ushort* afull  = (ushort*)(ws);                 // 25,600,512 B  50001 rows
    ushort* WfT    = (ushort*)(ws + 25600512);      //     65,536 B  B^T bf16
    ushort* rel_bf = (ushort*)(ws + 25666048);      //    128,256 B  501 rows
    int* deg       = (int*)(ws + 25794304);         //  6,400,000 B  deg[n*DEGS]
    uint* srcpk    = (uint*)(ws + 32194304);        // 12,800,000 B  slots [n*CAP+r]

    hipMemsetAsync(deg, 0, 6400000, stream);
    k_edge <<<3125,  256, 0, stream>>>(dst, src, etype, deg, srcpk);
    k_rest <<<3380,  256, 0, stream>>>(prev, node_id, afull, rel, rel_bf, Wn, Wl, WfT);
    k_agg  <<<12500, 256, 0, stream>>>(afull, rel_bf, srcpk, deg);
    k_mm   <<<391,   256, 0, stream>>>(afull, WfT, deg, We, out);
}

// Round 4
// 248.524 us; speedup vs baseline: 1.0169x; 1.0169x over previous
//
#include <hip/hip_runtime.h>
#include <hip/hip_bf16.h>
#include <stdint.h>

// Problem constants (from reference)
#define N_NODES 50000
#define N_EDGES 800000
#define N_ENTS  200000
#define N_RELS  500
#define DIM     128

#define DEGS 32   // deg counter stride (ints): 1 counter per 128B L2 line.
#define CAP  64   // slots per node. deg ~ Poisson(16); P(any node > 64) ~ 1e-20.

// invalid-edge record: points at zeroed dummy rows (afull row 50000, rel row 500)
#define ZERO_REC ((int)(50000u | (500u << 16)))

using f32x4  = __attribute__((ext_vector_type(4))) float;
using bf16x8 = __attribute__((ext_vector_type(8))) short;  // 8 bf16 = 4 VGPRs

static __device__ __forceinline__ ushort f_to_bf16(float f) {
    __hip_bfloat16 h = __float2bfloat16(f);
    return *reinterpret_cast<ushort*>(&h);
}
static __device__ __forceinline__ uint pack2(float a, float b) {
    return (uint)f_to_bf16(a) | ((uint)f_to_bf16(b) << 16);
}
static __device__ __forceinline__ float blo(uint u) { return __uint_as_float(u << 16); }
static __device__ __forceinline__ float bhi(uint u) { return __uint_as_float(u & 0xffff0000u); }

// ---------------------------------------------------------------------------
// K_FRONT: four jobs in one launch. r8: edge and gather jobs INTERLEAVED by
// block parity (was: all edge blocks then all gather blocks). Evidence r1<->r2:
// edge pass is latency-bound on atomicAdd-with-return (same atomic count at
// 1/4 threads cost +28us). Parity-mixing puts BW-bound gather waves on every
// CU from t=0 so they use the memory BW while edge waves sit in the atomic
// queue -> k_front approaches max(edge, gather) instead of sum.
// r3 lesson: do NOT split these into separate dispatches (serial stream, no
// overlap possible, +5us) — the merge IS the overlap mechanism.
//   blk [0,6250) even: edge idx=blk>>1: r=atomicAdd(&deg[dst*DEGS],1);
//                      srcpk[dst*CAP+r] = src|etype<<16   (1 edge/thread)
//   blk [0,6250) odd:  gather h = bf16(prev[node_id]) into h-half of afull
//                      afull row layout: [ apre(128) | h(128) ] bf16, stride 256
//   blk [6250,6504): weight-prep: B^T bf16 (WfT) + rel bf16
//   blk 6504:        zero the dummy rows (afull row 50000, rel_bf row 500)
__global__ __launch_bounds__(256) void k_front(
        const float* __restrict__ prev, const int* __restrict__ node_id,
        ushort* __restrict__ afull,
        const int* __restrict__ dst, const int* __restrict__ src,
        const int* __restrict__ etype,
        int* __restrict__ deg, uint* __restrict__ srcpk,
        const float* __restrict__ rel, ushort* __restrict__ rel_bf,
        const float* __restrict__ Wn, const float* __restrict__ Wl,
        ushort* __restrict__ WfT) {
    int blk = blockIdx.x;
    if (blk < 6250) {
        int idx = blk >> 1;
        if ((blk & 1) == 0) {
            int e = idx * 256 + threadIdx.x;
            if (e < N_EDGES) {
                int dn = dst[e];
                uint rec = (uint)src[e] | ((uint)etype[e] << 16);
                int r = atomicAdd(&deg[dn * DEGS], 1);
                if (r < CAP) srcpk[dn * CAP + r] = rec;
            }
        } else {
            int i = idx * 256 + threadIdx.x;        // 800,000 = N_NODES*16 exactly
            int row = i >> 4, c = (i & 15) * 8;
            int nid = node_id[row];
            const float* p = prev + (size_t)nid * DIM + c;
            float4 v0 = *(const float4*)p;
            float4 v1 = *(const float4*)(p + 4);
            uint4 w;
            w.x = pack2(v0.x, v0.y);
            w.y = pack2(v0.z, v0.w);
            w.z = pack2(v1.x, v1.y);
            w.w = pack2(v1.z, v1.w);
            *(uint4*)(afull + (size_t)row * 256 + 128 + c) = w;
        }
    } else if (blk < 6504) {
        int i = (blk - 6250) * 256 + threadIdx.x;
        if (i < 128 * 256) {            // WfT[n][k] = k<128 ? Wn[k][n] : Wl[k-128][n]
            int n = i >> 8, k = i & 255;
            float v = (k < 128) ? Wn[k * 128 + n] : Wl[(k - 128) * 128 + n];
            WfT[i] = f_to_bf16(v);
        } else {
            int j = i - 128 * 256;      // rel fp32 -> bf16, 2 elems/thread
            if (j < N_RELS * 64) {
                float2 v = *(const float2*)(rel + j * 2);
                *(uint*)(rel_bf + j * 2) = pack2(v.x, v.y);
            }
        }
    } else {
        int t = threadIdx.x;            // zero dummy rows (ws is 0xAA-poisoned)
        if (t < 128)       ((uint*)(afull + (size_t)50000 * 256))[t] = 0u;
        else if (t < 192)  ((uint*)(rel_bf + 500 * 128))[t - 128]    = 0u;
    }
}

// ---------------------------------------------------------------------------
// K_AGG: per-node aggregation, 1 wave per node. (exact r2 form — r3's
// 4-edge tail regressed ~6us: it swapped L1-hot dummy gathers for serial
// 2-load dependent iterations on the 46% of nodes with cnt%16 != 0.)
// apre[n] = bf16( (1/deg) * sum_{slots of n} (h[src_e] + rel[etype_e]) )
// Lane-group scheme: group g (lanes 16g..16g+15) covers an edge's FULL
// 256B h-row / rel-row with one dwordx4 per lane. Invalid slots point at
// zeroed dummy rows (no cndmask in the hot loop; dummies are L1-hot).
// 16 edges/iter: avg node (cnt=16) is a SINGLE trip with 8 dwordx4 in
// flight per lane -> max memory-level parallelism per wave.
__global__ __launch_bounds__(256) void k_agg(ushort* __restrict__ afull,
                                             const ushort* __restrict__ rel_bf,
                                             const uint* __restrict__ srcpk,
                                             const int* __restrict__ deg) {
    int wave = threadIdx.x >> 6, lane = threadIdx.x & 63;
    int n = blockIdx.x * 4 + wave;
    if (n >= N_NODES) return;
    int d = deg[n * DEGS];
    int cnt = min(d, CAP);
    int g = lane >> 4, q = lane & 15;           // group, quarter-position
    const ushort* hb = afull + 128 + q * 8;     // + srow*256
    const ushort* rb = rel_bf + q * 8;          // + t*128
    float acc[8] = {0.f, 0.f, 0.f, 0.f, 0.f, 0.f, 0.f, 0.f};

#define ACC4(hv, rv)                                              \
    acc[0] += blo(hv.x) + blo(rv.x); acc[1] += bhi(hv.x) + bhi(rv.x); \
    acc[2] += blo(hv.y) + blo(rv.y); acc[3] += bhi(hv.y) + bhi(rv.y); \
    acc[4] += blo(hv.z) + blo(rv.z); acc[5] += bhi(hv.z) + bhi(rv.z); \
    acc[6] += blo(hv.w) + blo(rv.w); acc[7] += bhi(hv.w) + bhi(rv.w);

    int rec = (lane < cnt) ? (int)srcpk[n * CAP + lane] : ZERO_REC;
    for (int j = 0; j < cnt; j += 16) {         // 16 edges per iter (4 per group)
        uint e0 = (uint)__shfl(rec, j + g);
        uint e1 = (uint)__shfl(rec, j + 4 + g);
        uint e2 = (uint)__shfl(rec, j + 8 + g);
        uint e3 = (uint)__shfl(rec, j + 12 + g);
        uint4 h0 = *(const uint4*)(hb + (size_t)(e0 & 0xffffu) * 256);
        uint4 r0 = *(const uint4*)(rb + (e0 >> 16) * 128);
        uint4 h1 = *(const uint4*)(hb + (size_t)(e1 & 0xffffu) * 256);
        uint4 r1 = *(const uint4*)(rb + (e1 >> 16) * 128);
        uint4 h2 = *(const uint4*)(hb + (size_t)(e2 & 0xffffu) * 256);
        uint4 r2 = *(const uint4*)(rb + (e2 >> 16) * 128);
        uint4 h3 = *(const uint4*)(hb + (size_t)(e3 & 0xffffu) * 256);
        uint4 r3 = *(const uint4*)(rb + (e3 >> 16) * 128);
        ACC4(h0, r0);
        ACC4(h1, r1);
        ACC4(h2, r2);
        ACC4(h3, r3);
    }
#undef ACC4

    // cross-group reduction: groups 0..3 hold partial sums of the same columns
#pragma unroll
    for (int i = 0; i < 8; i++) {
        acc[i] += __shfl_xor(acc[i], 16);
        acc[i] += __shfl_xor(acc[i], 32);
    }
    float norm = (d > 0) ? 1.0f / (float)d : 0.0f;
    if (g == 0) {                                // 16 lanes store the full row
        uint4 w;
        w.x = pack2(acc[0] * norm, acc[1] * norm);
        w.y = pack2(acc[2] * norm, acc[3] * norm);
        w.z = pack2(acc[4] * norm, acc[5] * norm);
        w.w = pack2(acc[6] * norm, acc[7] * norm);
        *(uint4*)(afull + (size_t)n * 256 + q * 8) = w;
    }
}

// ---------------------------------------------------------------------------
// K_MM: fused GEMM  out = relu( [apre|h] @ [Wn;Wl] ),  M=50000, N=128, K=256
// mfma_f32_16x16x32_bf16; each wave: 2 row-tiles x 8 col-tiles. fp32 output.
// Absorbs k_fixup: epilogue checks deg per row; deg==0 rows (expected ~0 of
// 50000) take a slow VALU path out = relu(h @ We).
// LDSK=264 B-reads verified conflict-free: each 8-lane b128 phase group
// (fixed quad, consecutive m) covers 8 distinct 4-bank windows.
#define LDSK 264   // padded k-stride (elems)
__global__ __launch_bounds__(256) void k_mm(const ushort* __restrict__ afull,
                                            const ushort* __restrict__ WfT,
                                            const int* __restrict__ deg,
                                            const float* __restrict__ We,
                                            float* __restrict__ out) {
    __shared__ ushort wl[128 * LDSK];   // 67,584 B
    for (int idx = threadIdx.x; idx < 128 * 32; idx += 256) {
        int n = idx >> 5, p = idx & 31;
        uint4 v = *(const uint4*)(WfT + n * 256 + p * 8);
        *(uint4*)(&wl[n * LDSK + p * 8]) = v;
    }
    __syncthreads();

    int wave = threadIdx.x >> 6, lane = threadIdx.x & 63;
    int m = lane & 15, quad = lane >> 4;
    int rowBase = blockIdx.x * 128 + wave * 32;

    f32x4 acc[2][8];
#pragma unroll
    for (int rt = 0; rt < 2; rt++)
#pragma unroll
        for (int ct = 0; ct < 8; ct++) acc[rt][ct] = f32x4{0.f, 0.f, 0.f, 0.f};

    int r0 = rowBase + m;      if (r0 > N_NODES - 1) r0 = N_NODES - 1;  // clamp tail
    int r1 = rowBase + 16 + m; if (r1 > N_NODES - 1) r1 = N_NODES - 1;
    const ushort* pa0 = afull + (size_t)r0 * 256 + quad * 8;
    const ushort* pa1 = afull + (size_t)r1 * 256 + quad * 8;

#pragma unroll
    for (int ks = 0; ks < 8; ks++) {
        bf16x8 a0 = *(const bf16x8*)(pa0 + ks * 32);   // A[m][k]: k = quad*8+j
        bf16x8 a1 = *(const bf16x8*)(pa1 + ks * 32);
#pragma unroll
        for (int ct = 0; ct < 8; ct++) {
            bf16x8 b = *(const bf16x8*)(&wl[(ct * 16 + m) * LDSK + ks * 32 + quad * 8]);
            acc[0][ct] = __builtin_amdgcn_mfma_f32_16x16x32_bf16(a0, b, acc[0][ct], 0, 0, 0);
            acc[1][ct] = __builtin_amdgcn_mfma_f32_16x16x32_bf16(a1, b, acc[1][ct], 0, 0, 0);
        }
    }

    // epilogue: C/D layout col=lane&15, row=(lane>>4)*4+reg
#pragma unroll
    for (int rt = 0; rt < 2; rt++) {
        int rbase = rowBase + rt * 16 + quad * 4;
#pragma unroll
        for (int reg = 0; reg < 4; reg++) {
            int grow = rbase + reg;
            if (grow < N_NODES) {
                if (__builtin_expect(deg[grow * DEGS] == 0, 0)) {
                    // rare: no in-edges -> out = relu(h @ evolve_loop_weight).
                    // 16 lanes of this quad share the row; lane m covers cols m+16ct.
#pragma unroll 1
                    for (int ct = 0; ct < 8; ct++) {
                        int col = ct * 16 + m;
                        float a = 0.f;
#pragma unroll 1
                        for (int k = 0; k < 128; k++) {
                            float hv = blo((uint)afull[(size_t)grow * 256 + 128 + k]);
                            a += hv * We[k * 128 + col];
                        }
                        out[(size_t)grow * 128 + col] = a > 0.f ? a : 0.f;
                    }
                } else {
#pragma unroll
                    for (int ct = 0; ct < 8; ct++) {
                        float v = acc[rt][ct][reg];
                        out[(size_t)grow * 128 + ct * 16 + m] = v > 0.f ? v : 0.f;
                    }
                }
            }
        }
    }
}

// ---------------------------------------------------------------------------
extern "C" void kernel_launch(void* const* d_in, const int* in_sizes, int n_in,
                              void* d_out, int out_size, void* d_ws, size_t ws_size,
                              hipStream_t stream) {
    const float* prev  = (const float*)d_in[0];  // prev_ent_embs   [200000,128] f32
    const float* rel   = (const float*)d_in[1];  // rel_embs        [500,128]    f32
    const float* Wl    = (const float*)d_in[2];  // loop_weight     [128,128]    f32
    const float* We    = (const float*)d_in[3];  // evolve_loop_w   [128,128]    f32
    const float* Wn    = (const float*)d_in[4];  // weight_neighbor [128,128]    f32
    const int* node_id = (const int*)d_in[5];    // [50000]  int32
    const int* src     = (const int*)d_in[6];    // [800000] int32
    const int* dst     = (const int*)d_in[7];    // [800000] int32
    const int* etype   = (const int*)d_in[8];    // [800000] int32
    float* out = (float*)d_out;                  // [50000,128] f32

    // workspace layout (~45 MB; afull/rel_bf each carry a zeroed dummy row)
    char* ws = (char*)d_ws;
    ushort* afull  = (ushort*)(ws);                 // 25,600,512 B  50001 rows
    ushort* WfT    = (ushort*)(ws + 25600512);      //     65,536 B  B^T bf16
    ushort* rel_bf = (ushort*)(ws + 25666048);      //    128,256 B  501 rows
    int* deg       = (int*)(ws + 25794304);         //  6,400,000 B  deg[n*DEGS]
    uint* srcpk    = (uint*)(ws + 32194304);        // 12,800,000 B  slots [n*CAP+r]

    hipMemsetAsync(deg, 0, 6400000, stream);
    k_front <<<6505,  256, 0, stream>>>(prev, node_id, afull, dst, src, etype,
                                        deg, srcpk, rel, rel_bf, Wn, Wl, WfT);
    k_agg   <<<12500, 256, 0, stream>>>(afull, rel_bf, srcpk, deg);
    k_mm    <<<391,   256, 0, stream>>>(afull, WfT, deg, We, out);
}

// Round 5
// 241.663 us; speedup vs baseline: 1.0458x; 1.0284x over previous
//
#include <hip/hip_runtime.h>
#include <hip/hip_bf16.h>
#include <stdint.h>

// Problem constants (from reference)
#define N_NODES 50000
#define N_EDGES 800000
#define N_ENTS  200000
#define N_RELS  500
#define DIM     128

#define DEGS 64   // deg counter stride (ints): 256B apart. History: 256/line ->
                  // 16/line -> 32 (one 128B line) each won. r9: if far-atomic
                  // serialization granule is the 256B channel-interleave granule
                  // (not the 128B line), DEGS=32 still pairs counters per granule;
                  // 64 gives each counter a private granule -> 2x slice parallelism.
#define CAP  64   // slots per node. deg ~ Poisson(16); P(any node > 64) ~ 1e-20.

// invalid-edge record: points at zeroed dummy rows (afull row 50000, rel row 500)
#define ZERO_REC ((int)(50000u | (500u << 16)))

using f32x4  = __attribute__((ext_vector_type(4))) float;
using bf16x8 = __attribute__((ext_vector_type(8))) short;  // 8 bf16 = 4 VGPRs

static __device__ __forceinline__ ushort f_to_bf16(float f) {
    __hip_bfloat16 h = __float2bfloat16(f);
    return *reinterpret_cast<ushort*>(&h);
}
static __device__ __forceinline__ uint pack2(float a, float b) {
    return (uint)f_to_bf16(a) | ((uint)f_to_bf16(b) << 16);
}
static __device__ __forceinline__ float blo(uint u) { return __uint_as_float(u << 16); }
static __device__ __forceinline__ float bhi(uint u) { return __uint_as_float(u & 0xffff0000u); }

// ---------------------------------------------------------------------------
// K_FRONT: four independent jobs in one launch, job-ordered blocks (r8 lesson:
// parity-interleaving edge+gather blocks CONTENDS (+7us) — gather streams
// lengthen atomic round-trips; block-order serial is faster. r3 lesson: do not
// split into separate dispatches either, +5us. r6 lesson: 1 edge/thread max
// TLP — 4 edges/thread serialized the atomic chains, +28us.)
//   blk [0,3125):    RANK+SLOT: r = atomicAdd(&deg[dst*DEGS],1);
//                    srcpk[dst*CAP+r] = src|etype<<16
//   blk [3125,6250): gather h = bf16(prev[node_id]) into h-half of afull rows
//                    afull row layout: [ apre (128) | h (128) ] bf16, stride 256
//   blk [6250,6504): weight-prep: B^T bf16 (WfT) + rel bf16
//   blk 6504:        zero the dummy rows (afull row 50000, rel_bf row 500)
__global__ __launch_bounds__(256) void k_front(
        const float* __restrict__ prev, const int* __restrict__ node_id,
        ushort* __restrict__ afull,
        const int* __restrict__ dst, const int* __restrict__ src,
        const int* __restrict__ etype,
        int* __restrict__ deg, uint* __restrict__ srcpk,
        const float* __restrict__ rel, ushort* __restrict__ rel_bf,
        const float* __restrict__ Wn, const float* __restrict__ Wl,
        ushort* __restrict__ WfT) {
    int blk = blockIdx.x;
    if (blk < 3125) {
        int e = blk * 256 + threadIdx.x;
        if (e < N_EDGES) {
            int dn = dst[e];
            uint rec = (uint)src[e] | ((uint)etype[e] << 16);
            int r = atomicAdd(&deg[dn * DEGS], 1);
            if (r < CAP) srcpk[dn * CAP + r] = rec;
        }
    } else if (blk < 6250) {
        int i = (blk - 3125) * 256 + threadIdx.x;   // 800,000 = N_NODES*16 exactly
        int row = i >> 4, c = (i & 15) * 8;
        int nid = node_id[row];
        const float* p = prev + (size_t)nid * DIM + c;
        float4 v0 = *(const float4*)p;
        float4 v1 = *(const float4*)(p + 4);
        uint4 w;
        w.x = pack2(v0.x, v0.y);
        w.y = pack2(v0.z, v0.w);
        w.z = pack2(v1.x, v1.y);
        w.w = pack2(v1.z, v1.w);
        *(uint4*)(afull + (size_t)row * 256 + 128 + c) = w;
    } else if (blk < 6504) {
        int i = (blk - 6250) * 256 + threadIdx.x;
        if (i < 128 * 256) {            // WfT[n][k] = k<128 ? Wn[k][n] : Wl[k-128][n]
            int n = i >> 8, k = i & 255;
            float v = (k < 128) ? Wn[k * 128 + n] : Wl[(k - 128) * 128 + n];
            WfT[i] = f_to_bf16(v);
        } else {
            int j = i - 128 * 256;      // rel fp32 -> bf16, 2 elems/thread
            if (j < N_RELS * 64) {
                float2 v = *(const float2*)(rel + j * 2);
                *(uint*)(rel_bf + j * 2) = pack2(v.x, v.y);
            }
        }
    } else {
        int t = threadIdx.x;            // zero dummy rows (ws is 0xAA-poisoned)
        if (t < 128)       ((uint*)(afull + (size_t)50000 * 256))[t] = 0u;
        else if (t < 192)  ((uint*)(rel_bf + 500 * 128))[t - 128]    = 0u;
    }
}

// ---------------------------------------------------------------------------
// K_AGG: per-node aggregation, 1 wave per node. (exact r2 form — r3's
// 4-edge tail regressed ~6us: serial 2-load iterations beat by L1-hot
// dummy gathers.)
// apre[n] = bf16( (1/deg) * sum_{slots of n} (h[src_e] + rel[etype_e]) )
// Lane-group scheme: group g (lanes 16g..16g+15) covers an edge's FULL
// 256B h-row / rel-row with one dwordx4 per lane. Invalid slots point at
// zeroed dummy rows (no cndmask in the hot loop; dummies are L1-hot).
// 16 edges/iter: avg node (cnt=16) is a SINGLE trip with 8 dwordx4 in
// flight per lane -> max memory-level parallelism per wave.
__global__ __launch_bounds__(256) void k_agg(ushort* __restrict__ afull,
                                             const ushort* __restrict__ rel_bf,
                                             const uint* __restrict__ srcpk,
                                             const int* __restrict__ deg) {
    int wave = threadIdx.x >> 6, lane = threadIdx.x & 63;
    int n = blockIdx.x * 4 + wave;
    if (n >= N_NODES) return;
    int d = deg[n * DEGS];
    int cnt = min(d, CAP);
    int g = lane >> 4, q = lane & 15;           // group, quarter-position
    const ushort* hb = afull + 128 + q * 8;     // + srow*256
    const ushort* rb = rel_bf + q * 8;          // + t*128
    float acc[8] = {0.f, 0.f, 0.f, 0.f, 0.f, 0.f, 0.f, 0.f};

#define ACC4(hv, rv)                                              \
    acc[0] += blo(hv.x) + blo(rv.x); acc[1] += bhi(hv.x) + bhi(rv.x); \
    acc[2] += blo(hv.y) + blo(rv.y); acc[3] += bhi(hv.y) + bhi(rv.y); \
    acc[4] += blo(hv.z) + blo(rv.z); acc[5] += bhi(hv.z) + bhi(rv.z); \
    acc[6] += blo(hv.w) + blo(rv.w); acc[7] += bhi(hv.w) + bhi(rv.w);

    int rec = (lane < cnt) ? (int)srcpk[n * CAP + lane] : ZERO_REC;
    for (int j = 0; j < cnt; j += 16) {         // 16 edges per iter (4 per group)
        uint e0 = (uint)__shfl(rec, j + g);
        uint e1 = (uint)__shfl(rec, j + 4 + g);
        uint e2 = (uint)__shfl(rec, j + 8 + g);
        uint e3 = (uint)__shfl(rec, j + 12 + g);
        uint4 h0 = *(const uint4*)(hb + (size_t)(e0 & 0xffffu) * 256);
        uint4 r0 = *(const uint4*)(rb + (e0 >> 16) * 128);
        uint4 h1 = *(const uint4*)(hb + (size_t)(e1 & 0xffffu) * 256);
        uint4 r1 = *(const uint4*)(rb + (e1 >> 16) * 128);
        uint4 h2 = *(const uint4*)(hb + (size_t)(e2 & 0xffffu) * 256);
        uint4 r2 = *(const uint4*)(rb + (e2 >> 16) * 128);
        uint4 h3 = *(const uint4*)(hb + (size_t)(e3 & 0xffffu) * 256);
        uint4 r3 = *(const uint4*)(rb + (e3 >> 16) * 128);
        ACC4(h0, r0);
        ACC4(h1, r1);
        ACC4(h2, r2);
        ACC4(h3, r3);
    }
#undef ACC4

    // cross-group reduction: groups 0..3 hold partial sums of the same columns
#pragma unroll
    for (int i = 0; i < 8; i++) {
        acc[i] += __shfl_xor(acc[i], 16);
        acc[i] += __shfl_xor(acc[i], 32);
    }
    float norm = (d > 0) ? 1.0f / (float)d : 0.0f;
    if (g == 0) {                                // 16 lanes store the full row
        uint4 w;
        w.x = pack2(acc[0] * norm, acc[1] * norm);
        w.y = pack2(acc[2] * norm, acc[3] * norm);
        w.z = pack2(acc[4] * norm, acc[5] * norm);
        w.w = pack2(acc[6] * norm, acc[7] * norm);
        *(uint4*)(afull + (size_t)n * 256 + q * 8) = w;
    }
}

// ---------------------------------------------------------------------------
// K_MM: fused GEMM  out = relu( [apre|h] @ [Wn;Wl] ),  M=50000, N=128, K=256
// mfma_f32_16x16x32_bf16; each wave: 2 row-tiles x 8 col-tiles. fp32 output.
// Absorbs k_fixup: epilogue checks deg per row; deg==0 rows (expected ~0 of
// 50000) take a slow VALU path out = relu(h @ We).
// LDSK=264 B-reads verified conflict-free: each 8-lane b128 phase group
// (fixed quad, consecutive m) covers 8 distinct 4-bank windows.
#define LDSK 264   // padded k-stride (elems)
__global__ __launch_bounds__(256) void k_mm(const ushort* __restrict__ afull,
                                            const ushort* __restrict__ WfT,
                                            const int* __restrict__ deg,
                                            const float* __restrict__ We,
                                            float* __restrict__ out) {
    __shared__ ushort wl[128 * LDSK];   // 67,584 B
    for (int idx = threadIdx.x; idx < 128 * 32; idx += 256) {
        int n = idx >> 5, p = idx & 31;
        uint4 v = *(const uint4*)(WfT + n * 256 + p * 8);
        *(uint4*)(&wl[n * LDSK + p * 8]) = v;
    }
    __syncthreads();

    int wave = threadIdx.x >> 6, lane = threadIdx.x & 63;
    int m = lane & 15, quad = lane >> 4;
    int rowBase = blockIdx.x * 128 + wave * 32;

    f32x4 acc[2][8];
#pragma unroll
    for (int rt = 0; rt < 2; rt++)
#pragma unroll
        for (int ct = 0; ct < 8; ct++) acc[rt][ct] = f32x4{0.f, 0.f, 0.f, 0.f};

    int r0 = rowBase + m;      if (r0 > N_NODES - 1) r0 = N_NODES - 1;  // clamp tail
    int r1 = rowBase + 16 + m; if (r1 > N_NODES - 1) r1 = N_NODES - 1;
    const ushort* pa0 = afull + (size_t)r0 * 256 + quad * 8;
    const ushort* pa1 = afull + (size_t)r1 * 256 + quad * 8;

#pragma unroll
    for (int ks = 0; ks < 8; ks++) {
        bf16x8 a0 = *(const bf16x8*)(pa0 + ks * 32);   // A[m][k]: k = quad*8+j
        bf16x8 a1 = *(const bf16x8*)(pa1 + ks * 32);
#pragma unroll
        for (int ct = 0; ct < 8; ct++) {
            bf16x8 b = *(const bf16x8*)(&wl[(ct * 16 + m) * LDSK + ks * 32 + quad * 8]);
            acc[0][ct] = __builtin_amdgcn_mfma_f32_16x16x32_bf16(a0, b, acc[0][ct], 0, 0, 0);
            acc[1][ct] = __builtin_amdgcn_mfma_f32_16x16x32_bf16(a1, b, acc[1][ct], 0, 0, 0);
        }
    }

    // epilogue: C/D layout col=lane&15, row=(lane>>4)*4+reg
#pragma unroll
    for (int rt = 0; rt < 2; rt++) {
        int rbase = rowBase + rt * 16 + quad * 4;
#pragma unroll
        for (int reg = 0; reg < 4; reg++) {
            int grow = rbase + reg;
            if (grow < N_NODES) {
                if (__builtin_expect(deg[grow * DEGS] == 0, 0)) {
                    // rare: no in-edges -> out = relu(h @ evolve_loop_weight).
                    // 16 lanes of this quad share the row; lane m covers cols m+16ct.
#pragma unroll 1
                    for (int ct = 0; ct < 8; ct++) {
                        int col = ct * 16 + m;
                        float a = 0.f;
#pragma unroll 1
                        for (int k = 0; k < 128; k++) {
                            float hv = blo((uint)afull[(size_t)grow * 256 + 128 + k]);
                            a += hv * We[k * 128 + col];
                        }
                        out[(size_t)grow * 128 + col] = a > 0.f ? a : 0.f;
                    }
                } else {
#pragma unroll
                    for (int ct = 0; ct < 8; ct++) {
                        float v = acc[rt][ct][reg];
                        out[(size_t)grow * 128 + ct * 16 + m] = v > 0.f ? v : 0.f;
                    }
                }
            }
        }
    }
}

// ---------------------------------------------------------------------------
extern "C" void kernel_launch(void* const* d_in, const int* in_sizes, int n_in,
                              void* d_out, int out_size, void* d_ws, size_t ws_size,
                              hipStream_t stream) {
    const float* prev  = (const float*)d_in[0];  // prev_ent_embs   [200000,128] f32
    const float* rel   = (const float*)d_in[1];  // rel_embs        [500,128]    f32
    const float* Wl    = (const float*)d_in[2];  // loop_weight     [128,128]    f32
    const float* We    = (const float*)d_in[3];  // evolve_loop_w   [128,128]    f32
    const float* Wn    = (const float*)d_in[4];  // weight_neighbor [128,128]    f32
    const int* node_id = (const int*)d_in[5];    // [50000]  int32
    const int* src     = (const int*)d_in[6];    // [800000] int32
    const int* dst     = (const int*)d_in[7];    // [800000] int32
    const int* etype   = (const int*)d_in[8];    // [800000] int32
    float* out = (float*)d_out;                  // [50000,128] f32

    // workspace layout (~52 MB; afull/rel_bf each carry a zeroed dummy row)
    char* ws = (char*)d_ws;
    ushort* afull  = (ushort*)(ws);                 // 25,600,512 B  50001 rows
    ushort* WfT    = (ushort*)(ws + 25600512);      //     65,536 B  B^T bf16
    ushort* rel_bf = (ushort*)(ws + 25666048);      //    128,256 B  501 rows
    int* deg       = (int*)(ws + 25794304);         // 12,800,000 B  deg[n*DEGS] (DEGS=64)
    uint* srcpk    = (uint*)(ws + 38594304);        // 12,800,000 B  slots [n*CAP+r]

    hipMemsetAsync(deg, 0, 12800000, stream);
    k_front <<<6505,  256, 0, stream>>>(prev, node_id, afull, dst, src, etype,
                                        deg, srcpk, rel, rel_bf, Wn, Wl, WfT);
    k_agg   <<<12500, 256, 0, stream>>>(afull, rel_bf, srcpk, deg);
    k_mm    <<<391,   256, 0, stream>>>(afull, WfT, deg, We, out);
}